// Round 2
// baseline (276.309 us; speedup 1.0000x reference)
//
#include <hip/hip_runtime.h>

#define N_ROWS 8192
#define N_LBL  1024

constexpr float C_COS_M  = (float)0.8775825618903728;   // cos(0.5)
constexpr float C_SIN_M  = (float)0.479425538604203;    // sin(0.5)
constexpr float C_THRESH = (float)-0.8775825618903728;  // cos(pi-0.5)
constexpr float C_MM     = (float)0.2397127693021015;   // sin(pi-0.5)*0.5
constexpr float C_ALPHA  = 0.1f;
constexpr float C_VALID  = 0.8f;
constexpr float C_K2E    = (float)(1.0 / (0.07 * 0.6931471805599453)); // 1/(T*ln2)
constexpr float C_LN2    = 0.6931471805599453f;

typedef short s16x8 __attribute__((ext_vector_type(8)));
typedef float f32x4 __attribute__((ext_vector_type(4)));

__device__ __forceinline__ unsigned f2bf(float f) {
    unsigned u = __float_as_uint(f);
    return (u + 0x7fffu + ((u >> 16) & 1u)) >> 16;   // RNE to bf16
}
__device__ __forceinline__ float bflo(unsigned u) { return __uint_as_float(u << 16); }
__device__ __forceinline__ float bfhi(unsigned u) { return __uint_as_float(u & 0xffff0000u); }

// ---------------- K1: row-normalize -> packed bf16; label histogram ----------------
__global__ void k_norm_hist(const float* __restrict__ f1, const float* __restrict__ f2,
                            const int* __restrict__ labels,
                            unsigned* __restrict__ f1n, unsigned* __restrict__ f2n,
                            int* __restrict__ hist) {
    int b = blockIdx.x, l = threadIdx.x;
    int row = (b < N_ROWS) ? b : (b - N_ROWS);
    const float* src = (b < N_ROWS) ? f1 : f2;
    unsigned* dst = (b < N_ROWS) ? f1n : f2n;
    float2 v = ((const float2*)(src + row * 128))[l];
    float ss = v.x * v.x + v.y * v.y;
    #pragma unroll
    for (int k = 1; k < 64; k <<= 1) ss += __shfl_xor(ss, k);
    float inv = 1.0f / fmaxf(sqrtf(ss), 1e-12f);
    dst[row * 64 + l] = f2bf(v.x * inv) | (f2bf(v.y * inv) << 16);
    if (b < N_ROWS && l == 0) atomicAdd(&hist[labels[row]], 1);
}

// ---------------- K2: scan 1024 bins (wave shfl) + scatter via LDS cursors ----------------
__global__ void k_scan_scatter(const int* __restrict__ hist, const int* __restrict__ labels,
                               int* __restrict__ offs, unsigned short* __restrict__ bucket) {
    __shared__ int loffs[N_LBL];
    __shared__ int wsum[16];
    int t = threadIdx.x, lane = t & 63, w = t >> 6;
    int v = hist[t];
    int x = v;
    #pragma unroll
    for (int k = 1; k < 64; k <<= 1) {
        int n = __shfl_up(x, k);
        if (lane >= k) x += n;
    }
    if (lane == 63) wsum[w] = x;
    __syncthreads();
    if (t < 16) {
        int own = wsum[t];
        int y = own;
        #pragma unroll
        for (int k = 1; k < 16; k <<= 1) {
            int n = __shfl_up(y, k);
            if (t >= k) y += n;
        }
        wsum[t] = y - own;   // exclusive wave offset
    }
    __syncthreads();
    int excl = x - v + wsum[w];
    loffs[t] = excl;
    offs[t] = excl;
    __syncthreads();
    for (int j = t; j < N_ROWS; j += 1024) {
        int p = atomicAdd(&loffs[labels[j]], 1);
        bucket[p] = (unsigned short)j;
    }
}

// ---------------- K3: positive pairs: sims, row sums (4 entries in parallel) ----------------
__global__ void k_passA(const unsigned* __restrict__ f1n, const unsigned* __restrict__ f2n,
                        const int* __restrict__ labels, const int* __restrict__ hist,
                        const int* __restrict__ offs, const unsigned short* __restrict__ bucket,
                        float* __restrict__ row_fp, float* __restrict__ row_sim,
                        float* __restrict__ simlist) {
    int i = blockIdx.x, lane = threadIdx.x;
    int g = lane >> 4, sl = lane & 15;
    uint4 a = ((const uint4*)(f1n + i * 64))[sl];
    float a0 = bflo(a.x), a1 = bfhi(a.x), a2 = bflo(a.y), a3 = bfhi(a.y);
    float a4 = bflo(a.z), a5 = bfhi(a.z), a6 = bflo(a.w), a7 = bfhi(a.w);
    int lab = labels[i];
    int cnt = hist[lab], st = offs[lab];
    float rs_sim = 0.f, rs_fp = 0.f;
    for (int e0 = 0; e0 < cnt; e0 += 4) {
        int e = e0 + g;
        bool val = e < cnt;
        int j = bucket[st + (val ? e : 0)];
        uint4 b = ((const uint4*)(f2n + j * 64))[sl];
        float p = a0 * bflo(b.x) + a1 * bfhi(b.x) + a2 * bflo(b.y) + a3 * bfhi(b.y)
                + a4 * bflo(b.z) + a5 * bfhi(b.z) + a6 * bflo(b.w) + a7 * bfhi(b.w);
        p += __shfl_xor(p, 1);
        p += __shfl_xor(p, 2);
        p += __shfl_xor(p, 4);
        p += __shfl_xor(p, 8);
        float s = fminf(1.f, fmaxf(-1.f, p));
        float ctm = s * C_COS_M - sqrtf(fmaxf(0.f, 1.f - s * s)) * C_SIN_M;
        float fpv = (s > C_THRESH) ? ctm : (s - C_MM);
        if (val) {
            rs_sim += s;
            rs_fp += fpv;
            if (sl == 0) simlist[i * 128 + e] = s;
        }
    }
    rs_sim += __shfl_xor(rs_sim, 16); rs_sim += __shfl_xor(rs_sim, 32);
    rs_fp  += __shfl_xor(rs_fp, 16);  rs_fp  += __shfl_xor(rs_fp, 32);
    if (lane == 0) { row_fp[i] = rs_fp; row_sim[i] = rs_sim; }
}

// ---------------- K4: row_target, t, weight_valid ----------------
__global__ void k_finalize(const float* __restrict__ row_fp, const float* __restrict__ row_sim,
                           const int* __restrict__ labels, const int* __restrict__ hist,
                           float* __restrict__ rt, float* __restrict__ tw) {
    int t = threadIdx.x;
    float ssum = 0.f, scnt = 0.f;
    for (int i = t; i < N_ROWS; i += 256) {
        int c = hist[labels[i]];
        rt[i] = row_fp[i] / (float)c;
        ssum += row_sim[i];
        scnt += (float)c;
    }
    #pragma unroll
    for (int k = 1; k < 64; k <<= 1) {
        ssum += __shfl_xor(ssum, k);
        scnt += __shfl_xor(scnt, k);
    }
    __shared__ float sa[4], sb[4];
    if ((t & 63) == 0) { sa[t >> 6] = ssum; sb[t >> 6] = scnt; }
    __syncthreads();
    if (t == 0) {
        float tv = C_ALPHA * ((sa[0] + sa[1] + sa[2] + sa[3]) / (sb[0] + sb[1] + sb[2] + sb[3]));
        tw[0] = tv;
        tw[1] = (tv > C_VALID) ? 1.f : 0.f;
    }
}

// ---------------- K5: dense pass — every entry treated as negative ----------------
template <bool WV>
__device__ __forceinline__ void epi_accum(const f32x4 (&acc)[4][4], const float (&rtv)[4][4],
                                          float (&lnp)[4][4], float tval) {
    #pragma unroll
    for (int mt = 0; mt < 4; ++mt)
        #pragma unroll
        for (int nt = 0; nt < 4; ++nt)
            #pragma unroll
            for (int r = 0; r < 4; ++r) {
                float s = acc[mt][nt][r];          // |s| < 1 always: clamp non-binding
                float u = C_K2E * s;
                float v = u * (tval + s);
                float arg = (s > rtv[mt][r]) ? v : u;
                float e = __builtin_amdgcn_exp2f(arg);
                if (WV) { float cz = fminf(fmaxf(s, 0.f), 1.f); e *= cz * cz + 1.f; }
                lnp[mt][r] += e;
            }
}

__global__ __launch_bounds__(256, 3) void k_passB(const unsigned* __restrict__ f1n,
                                                  const unsigned* __restrict__ f2n,
                                                  const float* __restrict__ rt,
                                                  const float* __restrict__ tw,
                                                  float* __restrict__ lnacc) {
    __shared__ __align__(16) unsigned char ldsA[32768];
    const int tid = threadIdx.x;
    const int wave = tid >> 6, lane = tid & 63;
    const int wr = wave >> 1, wc = wave & 1;
    const int quad = lane >> 4, l15 = lane & 15;
    const int rowbase = blockIdx.x * 128;
    const float tval = tw[0];
    const bool wv = (tw[1] != 0.f);

    // stage A tile ONCE (32KB), XOR-swizzled 16B chunks; single barrier in kernel
    {
        const uint4* src = (const uint4*)(f1n + rowbase * 64);
        #pragma unroll
        for (int it = 0; it < 8; ++it) {
            int chunk = it * 256 + tid;
            int row = chunk >> 4, q = chunk & 15;
            *((uint4*)(ldsA + row * 256 + ((q ^ (row & 15)) << 4))) = src[chunk];
        }
    }

    float rtv[4][4];
    #pragma unroll
    for (int mt = 0; mt < 4; ++mt)
        #pragma unroll
        for (int r = 0; r < 4; ++r)
            rtv[mt][r] = rt[rowbase + wr * 64 + mt * 16 + quad * 4 + r];

    __syncthreads();

    float lnp[4][4] = {};
    #pragma unroll 1
    for (int ctile = 0; ctile < 4; ++ctile) {
        // B fragments straight from global (L2-resident, shared across 64 blocks)
        const unsigned* bbase = f2n + (((blockIdx.y * 4 + ctile) * 128 + wc * 64) * 64);

        f32x4 zero = {0.f, 0.f, 0.f, 0.f};
        f32x4 acc[4][4];
        #pragma unroll
        for (int mt = 0; mt < 4; ++mt)
            #pragma unroll
            for (int nt = 0; nt < 4; ++nt) acc[mt][nt] = zero;

        #pragma unroll
        for (int ks = 0; ks < 4; ++ks) {
            s16x8 af[4], bfr[4];
            #pragma unroll
            for (int nt = 0; nt < 4; ++nt)
                bfr[nt] = *((const s16x8*)(bbase + (nt * 16 + l15) * 64 + (ks * 4 + quad) * 4));
            #pragma unroll
            for (int mt = 0; mt < 4; ++mt) {
                int row = wr * 64 + mt * 16 + l15, q = ks * 4 + quad;
                af[mt] = *((const s16x8*)(ldsA + row * 256 + ((q ^ (row & 15)) << 4)));
            }
            #pragma unroll
            for (int mt = 0; mt < 4; ++mt)
                #pragma unroll
                for (int nt = 0; nt < 4; ++nt)
                    acc[mt][nt] = __builtin_amdgcn_mfma_f32_16x16x32_bf16(af[mt], bfr[nt],
                                                                          acc[mt][nt], 0, 0, 0);
        }
        if (wv) epi_accum<true>(acc, rtv, lnp, tval);
        else    epi_accum<false>(acc, rtv, lnp, tval);
    }

    #pragma unroll
    for (int mt = 0; mt < 4; ++mt)
        #pragma unroll
        for (int r = 0; r < 4; ++r) {
            float v = lnp[mt][r];
            v += __shfl_xor(v, 1);
            v += __shfl_xor(v, 2);
            v += __shfl_xor(v, 4);
            v += __shfl_xor(v, 8);
            if (l15 == 0)
                atomicAdd(&lnacc[rowbase + wr * 64 + mt * 16 + quad * 4 + r], v);
        }
}

// ---------------- K6: per-row positive correction + loss term (8 rows/wave) ----------------
__global__ void k_lossC(const float* __restrict__ simlist, const int* __restrict__ labels,
                        const int* __restrict__ hist, const float* __restrict__ rt,
                        const float* __restrict__ tw, const float* __restrict__ lnacc,
                        float* __restrict__ rowloss) {
    int lane = threadIdx.x;
    int sub = lane >> 3, sl = lane & 7;
    int i = blockIdx.x * 8 + sub;
    int cnt = hist[labels[i]];
    if (cnt > 128) cnt = 128;
    float tval = tw[0];
    bool wv = (tw[1] != 0.f);
    float rti = rt[i];
    float lp = 0.f, den = 0.f;
    for (int e = sl; e < cnt; e += 8) {
        float s = simlist[i * 128 + e];
        // what k_passB added for this (pos) entry:
        float sh = (s > rti) ? s * (tval + s) : s;
        float en = __builtin_amdgcn_exp2f(C_K2E * sh);
        // true positive contribution:
        float ctm = s * C_COS_M - sqrtf(fmaxf(0.f, 1.f - s * s)) * C_SIN_M;
        float fp = (s > C_THRESH) ? ctm : (s - C_MM);
        float ep = __builtin_amdgcn_exp2f(C_K2E * fp);
        if (wv) {
            float cz = fminf(fmaxf(s, 0.f), 1.f);
            en *= cz * cz + 1.f;
            float d = 1.f - s;
            ep *= d * d + 1.f;
        }
        den -= en;
        lp += ep;
    }
    #pragma unroll
    for (int k = 1; k < 8; k <<= 1) {
        den += __shfl_xor(den, k);
        lp += __shfl_xor(lp, k);
    }
    if (sl == 0) {
        float ln = lnacc[i] + den;
        rowloss[i] = (__builtin_amdgcn_logf(lp + ln) - __builtin_amdgcn_logf(lp)) * C_LN2;
    }
}

// ---------------- K7: final scalar reduce ----------------
__global__ void k_reduce(const float* __restrict__ rowloss, float* __restrict__ out) {
    int t = threadIdx.x;
    float v = 0.f;
    for (int i = t; i < N_ROWS; i += 256) v += rowloss[i];
    #pragma unroll
    for (int k = 1; k < 64; k <<= 1) v += __shfl_xor(v, k);
    __shared__ float wsum[4];
    if ((t & 63) == 0) wsum[t >> 6] = v;
    __syncthreads();
    if (t == 0) out[0] = (wsum[0] + wsum[1] + wsum[2] + wsum[3]) * (1.0f / (float)N_ROWS);
}

extern "C" void kernel_launch(void* const* d_in, const int* in_sizes, int n_in,
                              void* d_out, int out_size, void* d_ws, size_t ws_size,
                              hipStream_t stream) {
    (void)in_sizes; (void)n_in; (void)out_size; (void)ws_size;
    const float* f1 = (const float*)d_in[0];
    const float* f2 = (const float*)d_in[1];
    const int* labels = (const int*)d_in[2];
    float* out = (float*)d_out;
    char* ws = (char*)d_ws;

    // ws layout (bytes)
    unsigned* f1n          = (unsigned*)(ws + 0);              // 2 MB  bf16-packed
    unsigned* f2n          = (unsigned*)(ws + 2097152);        // 2 MB
    float* simlist         = (float*)(ws + 4194304);           // 4 MB (128 sims/row cap)
    float* row_fp          = (float*)(ws + 8388608);           // 32 KB
    float* row_sim         = (float*)(ws + 8421376);           // 32 KB
    float* rt              = (float*)(ws + 8454144);           // 32 KB
    float* rowloss         = (float*)(ws + 8486912);           // 32 KB
    int* offs              = (int*)(ws + 8519680);             // 4 KB
    unsigned short* bucket = (unsigned short*)(ws + 8523776);  // 16 KB
    float* tw              = (float*)(ws + 8540160);           // 64 B  (t, weight_valid)
    float* lnacc           = (float*)(ws + 8540224);           // 32 KB  -- zeroed
    int* hist              = (int*)(ws + 8572992);             // 4 KB   -- zeroed

    hipMemsetAsync(ws + 8540224, 0, 36864, stream);

    k_norm_hist<<<dim3(2 * N_ROWS), dim3(64), 0, stream>>>(f1, f2, labels, f1n, f2n, hist);
    k_scan_scatter<<<dim3(1), dim3(1024), 0, stream>>>(hist, labels, offs, bucket);
    k_passA<<<dim3(N_ROWS), dim3(64), 0, stream>>>(f1n, f2n, labels, hist, offs, bucket,
                                                   row_fp, row_sim, simlist);
    k_finalize<<<dim3(1), dim3(256), 0, stream>>>(row_fp, row_sim, labels, hist, rt, tw);
    k_passB<<<dim3(64, 16), dim3(256), 0, stream>>>(f1n, f2n, rt, tw, lnacc);
    k_lossC<<<dim3(1024), dim3(64), 0, stream>>>(simlist, labels, hist, rt, tw, lnacc, rowloss);
    k_reduce<<<dim3(1), dim3(256), 0, stream>>>(rowloss, out);
}

// Round 3
// 128.396 us; speedup vs baseline: 2.1520x; 2.1520x over previous
//
#include <hip/hip_runtime.h>

#define N_ROWS 8192
#define N_LBL  1024

constexpr float C_COS_M  = (float)0.8775825618903728;   // cos(0.5)
constexpr float C_SIN_M  = (float)0.479425538604203;    // sin(0.5)
constexpr float C_THRESH = (float)-0.8775825618903728;  // cos(pi-0.5)
constexpr float C_MM     = (float)0.2397127693021015;   // sin(pi-0.5)*0.5
constexpr float C_ALPHA  = 0.1f;
constexpr float C_VALID  = 0.8f;
constexpr float C_K2E    = (float)(1.0 / (0.07 * 0.6931471805599453)); // 1/(T*ln2)
constexpr float C_LN2    = 0.6931471805599453f;

typedef short s16x8 __attribute__((ext_vector_type(8)));
typedef float f32x4 __attribute__((ext_vector_type(4)));

__device__ __forceinline__ unsigned f2bf(float f) {
    unsigned u = __float_as_uint(f);
    return (u + 0x7fffu + ((u >> 16) & 1u)) >> 16;   // RNE to bf16
}
__device__ __forceinline__ float bflo(unsigned u) { return __uint_as_float(u << 16); }
__device__ __forceinline__ float bfhi(unsigned u) { return __uint_as_float(u & 0xffff0000u); }

// async 16B global->LDS (lands at lds + lane*16)
__device__ __forceinline__ void gl_lds16(const unsigned* g, void* lds) {
    __builtin_amdgcn_global_load_lds(
        (const __attribute__((address_space(1))) unsigned*)g,
        (__attribute__((address_space(3))) unsigned*)lds, 16, 0, 0);
}

// ---------------- K1: row-normalize -> packed bf16; label histogram ----------------
__global__ void k_norm_hist(const float* __restrict__ f1, const float* __restrict__ f2,
                            const int* __restrict__ labels,
                            unsigned* __restrict__ f1n, unsigned* __restrict__ f2n,
                            int* __restrict__ hist) {
    int b = blockIdx.x * 4 + (threadIdx.x >> 6);
    int l = threadIdx.x & 63;
    int row = (b < N_ROWS) ? b : (b - N_ROWS);
    const float* src = (b < N_ROWS) ? f1 : f2;
    unsigned* dst = (b < N_ROWS) ? f1n : f2n;
    float2 v = ((const float2*)(src + row * 128))[l];
    float ss = v.x * v.x + v.y * v.y;
    #pragma unroll
    for (int k = 1; k < 64; k <<= 1) ss += __shfl_xor(ss, k);
    float inv = 1.0f / fmaxf(sqrtf(ss), 1e-12f);
    dst[row * 64 + l] = f2bf(v.x * inv) | (f2bf(v.y * inv) << 16);
    if (b < N_ROWS && l == 0) atomicAdd(&hist[labels[row]], 1);
}

// ---------------- K2: scan 1024 bins (wave shfl) + scatter via LDS cursors ----------------
__global__ void k_scan_scatter(const int* __restrict__ hist, const int* __restrict__ labels,
                               int* __restrict__ offs, unsigned short* __restrict__ bucket) {
    __shared__ int loffs[N_LBL];
    __shared__ int wsum[16];
    int t = threadIdx.x, lane = t & 63, w = t >> 6;
    int v = hist[t];
    int x = v;
    #pragma unroll
    for (int k = 1; k < 64; k <<= 1) {
        int n = __shfl_up(x, k);
        if (lane >= k) x += n;
    }
    if (lane == 63) wsum[w] = x;
    __syncthreads();
    if (t < 16) {
        int own = wsum[t];
        int y = own;
        #pragma unroll
        for (int k = 1; k < 16; k <<= 1) {
            int n = __shfl_up(y, k);
            if (t >= k) y += n;
        }
        wsum[t] = y - own;   // exclusive wave offset
    }
    __syncthreads();
    int excl = x - v + wsum[w];
    loffs[t] = excl;
    offs[t] = excl;
    __syncthreads();
    for (int j = t; j < N_ROWS; j += 1024) {
        int p = atomicAdd(&loffs[labels[j]], 1);
        bucket[p] = (unsigned short)j;
    }
}

// ---------------- K3: positive pairs: sims, rt[i], row_sim (4 entries in parallel) -------
__global__ void k_passA(const unsigned* __restrict__ f1n, const unsigned* __restrict__ f2n,
                        const int* __restrict__ labels, const int* __restrict__ hist,
                        const int* __restrict__ offs, const unsigned short* __restrict__ bucket,
                        float* __restrict__ rt, float* __restrict__ row_sim,
                        float* __restrict__ simlist) {
    int i = blockIdx.x, lane = threadIdx.x;
    int g = lane >> 4, sl = lane & 15;
    uint4 a = ((const uint4*)(f1n + i * 64))[sl];
    float a0 = bflo(a.x), a1 = bfhi(a.x), a2 = bflo(a.y), a3 = bfhi(a.y);
    float a4 = bflo(a.z), a5 = bfhi(a.z), a6 = bflo(a.w), a7 = bfhi(a.w);
    int lab = labels[i];
    int cnt = hist[lab], st = offs[lab];
    float rs_sim = 0.f, rs_fp = 0.f;
    for (int e0 = 0; e0 < cnt; e0 += 4) {
        int e = e0 + g;
        bool val = e < cnt;
        int j = bucket[st + (val ? e : 0)];
        uint4 b = ((const uint4*)(f2n + j * 64))[sl];
        float p = a0 * bflo(b.x) + a1 * bfhi(b.x) + a2 * bflo(b.y) + a3 * bfhi(b.y)
                + a4 * bflo(b.z) + a5 * bfhi(b.z) + a6 * bflo(b.w) + a7 * bfhi(b.w);
        p += __shfl_xor(p, 1);
        p += __shfl_xor(p, 2);
        p += __shfl_xor(p, 4);
        p += __shfl_xor(p, 8);
        float s = fminf(1.f, fmaxf(-1.f, p));
        float ctm = s * C_COS_M - sqrtf(fmaxf(0.f, 1.f - s * s)) * C_SIN_M;
        float fpv = (s > C_THRESH) ? ctm : (s - C_MM);
        if (val) {
            rs_sim += s;
            rs_fp += fpv;
            if (sl == 0) simlist[i * 128 + e] = s;
        }
    }
    rs_sim += __shfl_xor(rs_sim, 16); rs_sim += __shfl_xor(rs_sim, 32);
    rs_fp  += __shfl_xor(rs_fp, 16);  rs_fp  += __shfl_xor(rs_fp, 32);
    if (lane == 0) { rt[i] = rs_fp / (float)cnt; row_sim[i] = rs_sim; }
}

// ---------------- K4: t and weight_valid (sum row_sim; sum cnt = sum hist^2) -------------
__global__ void k_finalize(const float* __restrict__ row_sim, const int* __restrict__ hist,
                           float* __restrict__ tw) {
    int t = threadIdx.x;
    float ssum = 0.f, scnt = 0.f;
    for (int l = t; l < N_LBL; l += 256) {
        float h = (float)hist[l];
        scnt += h * h;
    }
    for (int i = t; i < N_ROWS; i += 256) ssum += row_sim[i];
    #pragma unroll
    for (int k = 1; k < 64; k <<= 1) {
        ssum += __shfl_xor(ssum, k);
        scnt += __shfl_xor(scnt, k);
    }
    __shared__ float sa[4], sb[4];
    if ((t & 63) == 0) { sa[t >> 6] = ssum; sb[t >> 6] = scnt; }
    __syncthreads();
    if (t == 0) {
        float tv = C_ALPHA * ((sa[0] + sa[1] + sa[2] + sa[3]) / (sb[0] + sb[1] + sb[2] + sb[3]));
        tw[0] = tv;
        tw[1] = (tv > C_VALID) ? 1.f : 0.f;
    }
}

// ---------------- K5: dense pass — every entry treated as negative ----------------
template <bool WV>
__device__ __forceinline__ void epi_accum(const f32x4 (&acc)[4][4], const float (&rtv)[4][4],
                                          float (&lnp)[4][4], float tval) {
    #pragma unroll
    for (int mt = 0; mt < 4; ++mt)
        #pragma unroll
        for (int nt = 0; nt < 4; ++nt)
            #pragma unroll
            for (int r = 0; r < 4; ++r) {
                float s = acc[mt][nt][r];          // |s| < 1 always: clamp non-binding
                float u = C_K2E * s;
                float v = u * (tval + s);
                float arg = (s > rtv[mt][r]) ? v : u;
                float e = __builtin_amdgcn_exp2f(arg);
                if (WV) { float cz = fminf(fmaxf(s, 0.f), 1.f); e *= cz * cz + 1.f; }
                lnp[mt][r] += e;
            }
}

__global__ __launch_bounds__(256, 2) void k_passB(const unsigned* __restrict__ f1n,
                                                  const unsigned* __restrict__ f2n,
                                                  const float* __restrict__ rt,
                                                  const float* __restrict__ tw,
                                                  float* __restrict__ lnacc) {
    __shared__ __align__(16) unsigned char ldsA[32768];
    __shared__ __align__(16) unsigned char ldsB[32768];
    const int tid = threadIdx.x;
    const int wave = tid >> 6, lane = tid & 63;
    const int wr = wave >> 1, wc = wave & 1;
    const int quad = lane >> 4, l15 = lane & 15;
    const int rowbase = blockIdx.x * 128;
    const float tval = tw[0];
    const bool wv = (tw[1] != 0.f);

    // staging geometry: chunk = it*256 + tid; row = it*16 + (tid>>4); q = tid&15.
    // LDS slot (row,q) receives GLOBAL chunk (row, q ^ (row&15)): swizzle on the read side.
    // (row&15) == (tid>>4)&15, constant across iterations.
    const int srow = tid >> 4;                 // 0..15 starting row
    const int sq   = (tid & 15) ^ (srow & 15); // swizzled source q
    const int goff = srow * 64 + sq * 4;       // uint offset of source chunk (it=0)
    const int loff = wave * 1024;              // LDS byte base (it=0) for this wave

    {   // stage A (32KB) + B ctile 0 (32KB), async
        const unsigned* gA = f1n + rowbase * 64 + goff;
        const unsigned* gB = f2n + (blockIdx.y * 512) * 64 + goff;
        #pragma unroll
        for (int it = 0; it < 8; ++it) {
            gl_lds16(gA + it * 1024, ldsA + loff + it * 4096);
            gl_lds16(gB + it * 1024, ldsB + loff + it * 4096);
        }
    }

    float rtv[4][4];
    #pragma unroll
    for (int mt = 0; mt < 4; ++mt)
        #pragma unroll
        for (int r = 0; r < 4; ++r)
            rtv[mt][r] = rt[rowbase + wr * 64 + mt * 16 + quad * 4 + r];

    __syncthreads();   // A and B0 resident

    float lnp[4][4] = {};
    #pragma unroll
    for (int ctile = 0; ctile < 4; ++ctile) {
        f32x4 zero = {0.f, 0.f, 0.f, 0.f};
        f32x4 acc[4][4];
        #pragma unroll
        for (int mt = 0; mt < 4; ++mt)
            #pragma unroll
            for (int nt = 0; nt < 4; ++nt) acc[mt][nt] = zero;

        #pragma unroll
        for (int ks = 0; ks < 4; ++ks) {
            s16x8 af[4], bfr[4];
            #pragma unroll
            for (int mt = 0; mt < 4; ++mt) {
                int row = wr * 64 + mt * 16 + l15, q = ks * 4 + quad;
                af[mt] = *((const s16x8*)(ldsA + row * 256 + ((q ^ (row & 15)) << 4)));
            }
            #pragma unroll
            for (int nt = 0; nt < 4; ++nt) {
                int row = wc * 64 + nt * 16 + l15, q = ks * 4 + quad;
                bfr[nt] = *((const s16x8*)(ldsB + row * 256 + ((q ^ (row & 15)) << 4)));
            }
            #pragma unroll
            for (int mt = 0; mt < 4; ++mt)
                #pragma unroll
                for (int nt = 0; nt < 4; ++nt)
                    acc[mt][nt] = __builtin_amdgcn_mfma_f32_16x16x32_bf16(af[mt], bfr[nt],
                                                                          acc[mt][nt], 0, 0, 0);
        }

        __syncthreads();   // all waves finished reading B(ctile)
        if (ctile < 3) {   // async-stage B(ctile+1); latency hides under epilogue below
            const unsigned* gB = f2n + (blockIdx.y * 512 + (ctile + 1) * 128) * 64 + goff;
            #pragma unroll
            for (int it = 0; it < 8; ++it)
                gl_lds16(gB + it * 1024, ldsB + loff + it * 4096);
        }

        if (wv) epi_accum<true>(acc, rtv, lnp, tval);
        else    epi_accum<false>(acc, rtv, lnp, tval);

        if (ctile < 3) __syncthreads();   // vmcnt drained here -> B(ctile+1) visible
    }

    #pragma unroll
    for (int mt = 0; mt < 4; ++mt)
        #pragma unroll
        for (int r = 0; r < 4; ++r) {
            float v = lnp[mt][r];
            v += __shfl_xor(v, 1);
            v += __shfl_xor(v, 2);
            v += __shfl_xor(v, 4);
            v += __shfl_xor(v, 8);
            if (l15 == 0)
                atomicAdd(&lnacc[rowbase + wr * 64 + mt * 16 + quad * 4 + r], v);
        }
}

// ---------------- K6: per-row positive correction + loss, fused final reduce -------------
__global__ void k_lossC(const float* __restrict__ simlist, const int* __restrict__ labels,
                        const int* __restrict__ hist, const float* __restrict__ rt,
                        const float* __restrict__ tw, const float* __restrict__ lnacc,
                        float* __restrict__ out) {
    int t = threadIdx.x;
    int sub = t >> 3, sl = t & 7;
    int i = blockIdx.x * 32 + sub;
    int cnt = hist[labels[i]];
    if (cnt > 128) cnt = 128;
    float tval = tw[0];
    bool wv = (tw[1] != 0.f);
    float rti = rt[i];
    float lp = 0.f, den = 0.f;
    for (int e = sl; e < cnt; e += 8) {
        float s = simlist[i * 128 + e];
        // what k_passB added for this (pos) entry:
        float sh = (s > rti) ? s * (tval + s) : s;
        float en = __builtin_amdgcn_exp2f(C_K2E * sh);
        // true positive contribution:
        float ctm = s * C_COS_M - sqrtf(fmaxf(0.f, 1.f - s * s)) * C_SIN_M;
        float fp = (s > C_THRESH) ? ctm : (s - C_MM);
        float ep = __builtin_amdgcn_exp2f(C_K2E * fp);
        if (wv) {
            float cz = fminf(fmaxf(s, 0.f), 1.f);
            en *= cz * cz + 1.f;
            float d = 1.f - s;
            ep *= d * d + 1.f;
        }
        den -= en;
        lp += ep;
    }
    #pragma unroll
    for (int k = 1; k < 8; k <<= 1) {
        den += __shfl_xor(den, k);
        lp += __shfl_xor(lp, k);
    }
    float ln = lnacc[i] + den;
    float rl = (__builtin_amdgcn_logf(lp + ln) - __builtin_amdgcn_logf(lp)) * C_LN2;
    // all 8 sub-lanes hold rl; sum rows across wave (each row counted once via xor 8,16,32)
    rl += __shfl_xor(rl, 8);
    rl += __shfl_xor(rl, 16);
    rl += __shfl_xor(rl, 32);
    __shared__ float sa[4];
    if ((t & 63) == 0) sa[t >> 6] = rl;
    __syncthreads();
    if (t == 0)
        atomicAdd(out, (sa[0] + sa[1] + sa[2] + sa[3]) * (1.0f / (float)N_ROWS));
}

extern "C" void kernel_launch(void* const* d_in, const int* in_sizes, int n_in,
                              void* d_out, int out_size, void* d_ws, size_t ws_size,
                              hipStream_t stream) {
    (void)in_sizes; (void)n_in; (void)out_size; (void)ws_size;
    const float* f1 = (const float*)d_in[0];
    const float* f2 = (const float*)d_in[1];
    const int* labels = (const int*)d_in[2];
    float* out = (float*)d_out;
    char* ws = (char*)d_ws;

    // ws layout (bytes)
    unsigned* f1n          = (unsigned*)(ws + 0);              // 2 MB  bf16-packed
    unsigned* f2n          = (unsigned*)(ws + 2097152);        // 2 MB
    float* simlist         = (float*)(ws + 4194304);           // 4 MB (128 sims/row cap)
    float* row_sim         = (float*)(ws + 8388608);           // 32 KB
    float* rt              = (float*)(ws + 8421376);           // 32 KB
    int* offs              = (int*)(ws + 8454144);             // 4 KB
    unsigned short* bucket = (unsigned short*)(ws + 8458240);  // 16 KB
    float* tw              = (float*)(ws + 8474624);           // 64 B  (t, weight_valid)
    float* lnacc           = (float*)(ws + 8474688);           // 32 KB  -- zeroed
    int* hist              = (int*)(ws + 8507456);             // 4 KB   -- zeroed

    hipMemsetAsync(ws + 8474688, 0, 36864, stream);
    hipMemsetAsync(out, 0, 4, stream);

    k_norm_hist<<<dim3(4096), dim3(256), 0, stream>>>(f1, f2, labels, f1n, f2n, hist);
    k_scan_scatter<<<dim3(1), dim3(1024), 0, stream>>>(hist, labels, offs, bucket);
    k_passA<<<dim3(N_ROWS), dim3(64), 0, stream>>>(f1n, f2n, labels, hist, offs, bucket,
                                                   rt, row_sim, simlist);
    k_finalize<<<dim3(1), dim3(256), 0, stream>>>(row_sim, hist, tw);
    k_passB<<<dim3(64, 16), dim3(256), 0, stream>>>(f1n, f2n, rt, tw, lnacc);
    k_lossC<<<dim3(256), dim3(256), 0, stream>>>(simlist, labels, hist, rt, tw, lnacc, out);
}